// Round 1
// baseline (11486.607 us; speedup 1.0000x reference)
//
#include <hip/hip_runtime.h>
#include <hip/hip_bf16.h>
#include <stdint.h>

#define B_    64
#define T_    512
#define H_    512
#define G_    2048    // 4*H
#define TAGS_ 20

typedef __hip_bfloat16 bf16;
typedef __bf16 bf16x8 __attribute__((ext_vector_type(8)));
typedef float  f32x4  __attribute__((ext_vector_type(4)));

__device__ __forceinline__ float sigmoidf_(float x) { return 1.0f / (1.0f + __expf(-x)); }

// ---------------- prep kernels ----------------

__global__ void k_zero(uint32_t* __restrict__ p, int n) {
    for (int i = blockIdx.x * blockDim.x + threadIdx.x; i < n; i += gridDim.x * blockDim.x)
        p[i] = 0u;
}

__global__ void k_f2b(const float* __restrict__ s, bf16* __restrict__ d, int n) {
    for (int i = blockIdx.x * blockDim.x + threadIdx.x; i < n; i += gridDim.x * blockDim.x)
        d[i] = __float2bfloat16(s[i]);
}

__global__ void k_addb(const float* __restrict__ a, const float* __restrict__ b,
                       float* __restrict__ o, int n) {
    for (int i = blockIdx.x * blockDim.x + threadIdx.x; i < n; i += gridDim.x * blockDim.x)
        o[i] = a[i] + b[i];
}

__global__ __launch_bounds__(256) void k_lens(const int* __restrict__ x, int* __restrict__ lens) {
    int b = blockIdx.x;
    int cnt = 0;
    for (int tpos = threadIdx.x; tpos < T_; tpos += 256)
        cnt += (x[(size_t)b * T_ + tpos] == 0) ? 1 : 0;
    #pragma unroll
    for (int off = 32; off; off >>= 1) cnt += __shfl_xor(cnt, off);
    __shared__ int tot;
    if (threadIdx.x == 0) tot = 0;
    __syncthreads();
    if ((threadIdx.x & 63) == 0) atomicAdd(&tot, cnt);
    __syncthreads();
    if (threadIdx.x == 0) lens[b] = T_ - tot;
}

// E[t][b][d] = bf16(emb[x[b][t]][d])
__global__ void k_gather(const int* __restrict__ x, const float* __restrict__ emb,
                         bf16* __restrict__ E) {
    int t = blockIdx.x, b = blockIdx.y;
    int tok = x[(size_t)b * T_ + t];
    const float* src = emb + (size_t)tok * H_;
    bf16* dst = E + ((size_t)t * B_ + b) * H_;
    for (int d = threadIdx.x; d < H_; d += blockDim.x)
        dst[d] = __float2bfloat16(src[d]);
}

// ---------------- fused two-layer LSTM step ----------------
// Launch t: blocks 0..31 do layer-0 step t (t<T); blocks 32..63 do layer-1 step t-1 (t>=1).
// h state ping-pong: hs[s] lives in slot (s+1)&1. Layer-1 reads hs0[t-1] (slot t&1),
// while layer-0 writes slot (t+1)&1 -> disjoint, no intra-launch race.
__global__ __launch_bounds__(256) void k_step(
    int t,
    const bf16* __restrict__ E,
    const bf16* __restrict__ W0x, const bf16* __restrict__ W0h, const float* __restrict__ bias0,
    const bf16* __restrict__ W1x, const bf16* __restrict__ W1h, const float* __restrict__ bias1,
    bf16* __restrict__ h0buf, float* __restrict__ c0,
    bf16* __restrict__ h1buf, float* __restrict__ c1,
    float* __restrict__ last1, const int* __restrict__ lens)
{
    const int blk   = blockIdx.x;
    const int layer = blk >> 5;
    const int nb    = blk & 31;

    const bf16 *Ax, *Wx, *Wh, *hread;
    bf16* hwrite;
    const float* bias;
    float* c;
    int tt;

    if (layer == 0) {
        if (t >= T_) return;
        tt = t;
        Ax = E + (size_t)t * (B_ * H_);
        Wx = W0x; Wh = W0h; bias = bias0; c = c0;
        hread  = h0buf + (size_t)(t & 1) * (B_ * H_);
        hwrite = h0buf + (size_t)((t + 1) & 1) * (B_ * H_);
    } else {
        if (t == 0) return;
        tt = t - 1;
        Ax = h0buf + (size_t)(t & 1) * (B_ * H_);      // hs0[t-1]
        Wx = W1x; Wh = W1h; bias = bias1; c = c1;
        hread  = h1buf + (size_t)(tt & 1) * (B_ * H_);
        hwrite = h1buf + (size_t)((tt + 1) & 1) * (B_ * H_);
    }

    const int lane = threadIdx.x & 63;
    const int wave = threadIdx.x >> 6;     // 4 waves: batch tiles of 16
    const int l15  = lane & 15;
    const int kq   = (lane >> 4) * 8;      // k offset within 32-chunk
    const int arow = wave * 16 + l15;      // A-frag row (batch)
    const int jc   = nb * 16 + l15;        // hidden col (D col / W row offset)

    f32x4 acc[4];
    #pragma unroll
    for (int q = 0; q < 4; ++q) acc[q] = f32x4{0.f, 0.f, 0.f, 0.f};

    const bf16* aPtr = Ax    + (size_t)arow * H_ + kq;
    const bf16* hPtr = hread + (size_t)arow * H_ + kq;

    // x-part: gates += A_x @ W_x^T
    #pragma unroll 4
    for (int k0 = 0; k0 < H_; k0 += 32) {
        bf16x8 a = *reinterpret_cast<const bf16x8*>(aPtr + k0);
        #pragma unroll
        for (int q = 0; q < 4; ++q) {
            const bf16* wp = Wx + (size_t)(q * H_ + jc) * H_ + k0 + kq;
            bf16x8 bb = *reinterpret_cast<const bf16x8*>(wp);
            acc[q] = __builtin_amdgcn_mfma_f32_16x16x32_bf16(a, bb, acc[q], 0, 0, 0);
        }
    }
    // h-part: gates += h @ W_h^T
    #pragma unroll 4
    for (int k0 = 0; k0 < H_; k0 += 32) {
        bf16x8 a = *reinterpret_cast<const bf16x8*>(hPtr + k0);
        #pragma unroll
        for (int q = 0; q < 4; ++q) {
            const bf16* wp = Wh + (size_t)(q * H_ + jc) * H_ + k0 + kq;
            bf16x8 bb = *reinterpret_cast<const bf16x8*>(wp);
            acc[q] = __builtin_amdgcn_mfma_f32_16x16x32_bf16(a, bb, acc[q], 0, 0, 0);
        }
    }

    const float bi_ = bias[0 * H_ + jc];
    const float bf_ = bias[1 * H_ + jc];
    const float bg_ = bias[2 * H_ + jc];
    const float bo_ = bias[3 * H_ + jc];
    const int rbase = wave * 16 + (lane >> 4) * 4;   // D rows: (lane>>4)*4 + r

    #pragma unroll
    for (int r = 0; r < 4; ++r) {
        int bi = rbase + r;
        float gi = sigmoidf_(acc[0][r] + bi_);
        float gf = sigmoidf_(acc[1][r] + bf_);
        float gg = tanhf   (acc[2][r] + bg_);
        float go = sigmoidf_(acc[3][r] + bo_);
        size_t idx = (size_t)bi * H_ + jc;
        float cn = gf * c[idx] + gi * gg;
        float hn = go * tanhf(cn);
        c[idx] = cn;
        hwrite[idx] = __float2bfloat16(hn);
        if (layer == 1 && tt == lens[bi] - 1) last1[idx] = hn;
    }
}

// out[b][tag] = last1[b] . Wout[tag] + bout[tag]   (fp32)
__global__ __launch_bounds__(64) void k_out(const float* __restrict__ last1,
                                            const float* __restrict__ Wout,
                                            const float* __restrict__ bout,
                                            float* __restrict__ out) {
    int b = blockIdx.x, tg = blockIdx.y, lane = threadIdx.x;
    float s = 0.f;
    for (int d = lane; d < H_; d += 64)
        s += last1[(size_t)b * H_ + d] * Wout[(size_t)tg * H_ + d];
    #pragma unroll
    for (int off = 32; off; off >>= 1) s += __shfl_xor(s, off);
    if (lane == 0) out[b * TAGS_ + tg] = s + bout[tg];
}

// ---------------- host ----------------

extern "C" void kernel_launch(void* const* d_in, const int* in_sizes, int n_in,
                              void* d_out, int out_size, void* d_ws, size_t ws_size,
                              hipStream_t stream)
{
    const int*   x    = (const int*)  d_in[0];
    const float* emb  = (const float*)d_in[1];
    const float* Wih0 = (const float*)d_in[2];
    const float* Whh0 = (const float*)d_in[3];
    const float* bih0 = (const float*)d_in[4];
    const float* bhh0 = (const float*)d_in[5];
    const float* Wih1 = (const float*)d_in[6];
    const float* Whh1 = (const float*)d_in[7];
    const float* bih1 = (const float*)d_in[8];
    const float* bhh1 = (const float*)d_in[9];
    const float* Wout = (const float*)d_in[10];
    const float* bout = (const float*)d_in[11];
    float* out = (float*)d_out;

    char* p = (char*)d_ws;
    bf16* E    = (bf16*)p;  p += (size_t)T_ * B_ * H_ * 2;      // 32 MB
    bf16* W0x  = (bf16*)p;  p += (size_t)G_ * H_ * 2;
    bf16* W0h  = (bf16*)p;  p += (size_t)G_ * H_ * 2;
    bf16* W1x  = (bf16*)p;  p += (size_t)G_ * H_ * 2;
    bf16* W1h  = (bf16*)p;  p += (size_t)G_ * H_ * 2;
    float* bias0 = (float*)p; p += (size_t)G_ * 4;
    float* bias1 = (float*)p; p += (size_t)G_ * 4;
    char* zbase = p;                                            // zeroed region start
    bf16* h0buf = (bf16*)p; p += (size_t)2 * B_ * H_ * 2;
    bf16* h1buf = (bf16*)p; p += (size_t)2 * B_ * H_ * 2;
    float* c0    = (float*)p; p += (size_t)B_ * H_ * 4;
    float* c1    = (float*)p; p += (size_t)B_ * H_ * 4;
    float* last1 = (float*)p; p += (size_t)B_ * H_ * 4;
    size_t zbytes = (size_t)(p - zbase);
    int* lens = (int*)p; p += 256;

    k_zero<<<dim3(160), dim3(256), 0, stream>>>((uint32_t*)zbase, (int)(zbytes / 4));
    k_lens<<<dim3(B_), dim3(256), 0, stream>>>(x, lens);
    k_f2b<<<dim3(512), dim3(256), 0, stream>>>(Wih0, W0x, G_ * H_);
    k_f2b<<<dim3(512), dim3(256), 0, stream>>>(Whh0, W0h, G_ * H_);
    k_f2b<<<dim3(512), dim3(256), 0, stream>>>(Wih1, W1x, G_ * H_);
    k_f2b<<<dim3(512), dim3(256), 0, stream>>>(Whh1, W1h, G_ * H_);
    k_addb<<<dim3(8), dim3(256), 0, stream>>>(bih0, bhh0, bias0, G_);
    k_addb<<<dim3(8), dim3(256), 0, stream>>>(bih1, bhh1, bias1, G_);
    k_gather<<<dim3(T_, B_), dim3(256), 0, stream>>>(x, emb, E);

    for (int t = 0; t <= T_; ++t) {
        k_step<<<dim3(64), dim3(256), 0, stream>>>(t, E,
                                                   W0x, W0h, bias0,
                                                   W1x, W1h, bias1,
                                                   h0buf, c0, h1buf, c1,
                                                   last1, lens);
    }

    k_out<<<dim3(B_, TAGS_), dim3(64), 0, stream>>>(last1, Wout, bout, out);
}

// Round 2
// 5348.630 us; speedup vs baseline: 2.1476x; 2.1476x over previous
//
#include <hip/hip_runtime.h>
#include <hip/hip_bf16.h>
#include <stdint.h>

#define B_    64
#define T_    512
#define H_    512
#define G_    2048    // 4*H
#define TAGS_ 20

typedef __hip_bfloat16 bf16;
typedef __bf16 bf16x8 __attribute__((ext_vector_type(8)));
typedef float  f32x4  __attribute__((ext_vector_type(4)));

__device__ __forceinline__ float sigmoidf_(float x) { return 1.0f / (1.0f + __expf(-x)); }

// ---------------- prep kernels ----------------

__global__ void k_zero(uint32_t* __restrict__ p, int n) {
    for (int i = blockIdx.x * blockDim.x + threadIdx.x; i < n; i += gridDim.x * blockDim.x)
        p[i] = 0u;
}

__global__ void k_f2b(const float* __restrict__ s, bf16* __restrict__ d, int n) {
    for (int i = blockIdx.x * blockDim.x + threadIdx.x; i < n; i += gridDim.x * blockDim.x)
        d[i] = __float2bfloat16(s[i]);
}

__global__ void k_addb(const float* __restrict__ a, const float* __restrict__ b,
                       float* __restrict__ o, int n) {
    for (int i = blockIdx.x * blockDim.x + threadIdx.x; i < n; i += gridDim.x * blockDim.x)
        o[i] = a[i] + b[i];
}

__global__ __launch_bounds__(256) void k_lens(const int* __restrict__ x, int* __restrict__ lens) {
    int b = blockIdx.x;
    int cnt = 0;
    for (int tpos = threadIdx.x; tpos < T_; tpos += 256)
        cnt += (x[(size_t)b * T_ + tpos] == 0) ? 1 : 0;
    #pragma unroll
    for (int off = 32; off; off >>= 1) cnt += __shfl_xor(cnt, off);
    __shared__ int tot;
    if (threadIdx.x == 0) tot = 0;
    __syncthreads();
    if ((threadIdx.x & 63) == 0) atomicAdd(&tot, cnt);
    __syncthreads();
    if (threadIdx.x == 0) lens[b] = T_ - tot;
}

// E[t][b][d] = bf16(emb[x[b][t]][d])
__global__ void k_gather(const int* __restrict__ x, const float* __restrict__ emb,
                         bf16* __restrict__ E) {
    int t = blockIdx.x, b = blockIdx.y;
    int tok = x[(size_t)b * T_ + t];
    const float* src = emb + (size_t)tok * H_;
    bf16* dst = E + ((size_t)t * B_ + b) * H_;
    for (int d = threadIdx.x; d < H_; d += blockDim.x)
        dst[d] = __float2bfloat16(src[d]);
}

// ---------------- persistent 2-layer LSTM ----------------
// 256 blocks x 256 threads. block = (layer, mtile, strip); wave = gate.
// Weights register-resident (32 bf16x8 frags/wave). c-state in registers.
// Sync: per-(layer,mtile) group counters, agent-scope fences, 8-slot h rings.
__global__ __launch_bounds__(256, 1) void k_lstm(
    const bf16* __restrict__ E,
    const bf16* __restrict__ W0x, const bf16* __restrict__ W0h, const float* __restrict__ bias0,
    const bf16* __restrict__ W1x, const bf16* __restrict__ W1h, const float* __restrict__ bias1,
    bf16* __restrict__ h0ring, bf16* __restrict__ h1ring,
    float* __restrict__ last1, const int* __restrict__ lens,
    int* __restrict__ counters)
{
    const int bid   = blockIdx.x;
    const int layer = bid >> 7;          // 0..1
    const int m     = (bid >> 5) & 3;    // batch tile (16 rows)
    const int s     = bid & 31;          // hidden strip (16 cols)
    const int tid   = threadIdx.x;
    const int lane  = tid & 63;
    const int q     = tid >> 6;          // wave = gate
    const int l15   = lane & 15;
    const int kq    = (lane >> 4) * 8;

    // ---- load this wave's weights into registers (persist across steps) ----
    const bf16* Wx = layer ? W1x : W0x;
    const bf16* Wh = layer ? W1h : W0h;
    const int jc = s * 16 + l15;                       // hidden col in [0,512)
    bf16x8 w[32];
    #pragma unroll
    for (int kc = 0; kc < 16; ++kc)
        w[kc] = *reinterpret_cast<const bf16x8*>(Wx + ((size_t)(q * H_ + jc)) * H_ + kc * 32 + kq);
    #pragma unroll
    for (int kc = 0; kc < 16; ++kc)
        w[16 + kc] = *reinterpret_cast<const bf16x8*>(Wh + ((size_t)(q * H_ + jc)) * H_ + kc * 32 + kq);

    __shared__ float glds[4][16][20];   // [gate][j][row(+pad)] : 2-way max bank alias

    // ---- elementwise thread mapping: one (b,j) per thread, c in register ----
    const int eb   = tid >> 4;          // local batch row 0..15
    const int ej   = tid & 15;          // local col 0..15
    const int brow = m * 16 + eb;
    const int jcol = s * 16 + ej;
    float c_reg = 0.f;
    const float* bias = layer ? bias1 : bias0;
    const float bi0 = bias[0 * H_ + jcol];
    const float bi1 = bias[1 * H_ + jcol];
    const float bi2 = bias[2 * H_ + jcol];
    const float bi3 = bias[3 * H_ + jcol];
    int target = lens[brow] - 1;
    if (target < 0) target = T_ - 1;    // python -1 wrap

    int* ctr_own   = counters + (layer * 4 + m) * 32;
    int* ctr_other = counters + ((1 - layer) * 4 + m) * 32;

    const int arow = m * 16 + l15;      // A-fragment row
    bf16* myring = layer ? h1ring : h0ring;

    for (int tt = 0; tt < T_; ++tt) {
        // ---- wait for dependencies ----
        if (tid == 0) {
            const int own_t = 32 * tt;                              // groupmates done step tt-1
            const int oth_t = layer ? 32 * (tt + 1)                 // l1: l0 finished step tt
                                    : 32 * (tt - 7);                // l0: ring flow control
            while (__hip_atomic_load(ctr_own,   __ATOMIC_RELAXED, __HIP_MEMORY_SCOPE_AGENT) < own_t)
                __builtin_amdgcn_s_sleep(1);
            while (__hip_atomic_load(ctr_other, __ATOMIC_RELAXED, __HIP_MEMORY_SCOPE_AGENT) < oth_t)
                __builtin_amdgcn_s_sleep(1);
            __builtin_amdgcn_fence(__ATOMIC_ACQUIRE, "agent");
        }
        __syncthreads();

        // ---- A sources: x-part and h-part, both [64][512] bf16 row-major ----
        const bf16* xsrc = layer ? (h0ring + (size_t)(tt & 7) * (B_ * H_))
                                 : (E + (size_t)tt * (B_ * H_));
        const bf16* hsrc = myring + (size_t)((tt - 1) & 7) * (B_ * H_);
        const bf16* xp = xsrc + (size_t)arow * H_ + kq;
        const bf16* hp = hsrc + (size_t)arow * H_ + kq;

        f32x4 acc[4];
        #pragma unroll
        for (int i = 0; i < 4; ++i) acc[i] = f32x4{0.f, 0.f, 0.f, 0.f};

        #pragma unroll
        for (int kc = 0; kc < 16; ++kc) {
            bf16x8 A = *reinterpret_cast<const bf16x8*>(xp + kc * 32);
            acc[kc & 3] = __builtin_amdgcn_mfma_f32_16x16x32_bf16(A, w[kc], acc[kc & 3], 0, 0, 0);
        }
        #pragma unroll
        for (int kc = 0; kc < 16; ++kc) {
            bf16x8 A = *reinterpret_cast<const bf16x8*>(hp + kc * 32);
            acc[kc & 3] = __builtin_amdgcn_mfma_f32_16x16x32_bf16(A, w[16 + kc], acc[kc & 3], 0, 0, 0);
        }
        f32x4 g = (acc[0] + acc[1]) + (acc[2] + acc[3]);

        // ---- gate exchange via LDS: wave q writes its 16x16 tile ----
        const int rb = (lane >> 4) * 4;
        *reinterpret_cast<f32x4*>(&glds[q][l15][rb]) = g;
        __syncthreads();

        // ---- elementwise LSTM update ----
        float gi = sigmoidf_(glds[0][ej][eb] + bi0);
        float gf = sigmoidf_(glds[1][ej][eb] + bi1);
        float gg = tanhf   (glds[2][ej][eb] + bi2);
        float go = sigmoidf_(glds[3][ej][eb] + bi3);
        c_reg = gf * c_reg + gi * gg;
        float hn = go * tanhf(c_reg);
        myring[(size_t)(tt & 7) * (B_ * H_) + (size_t)brow * H_ + jcol] = __float2bfloat16(hn);
        if (layer == 1 && tt == target)
            last1[(size_t)brow * H_ + jcol] = hn;
        __syncthreads();

        // ---- publish step completion ----
        if (tid == 0) {
            __builtin_amdgcn_fence(__ATOMIC_RELEASE, "agent");
            __hip_atomic_fetch_add(ctr_own, 1, __ATOMIC_RELAXED, __HIP_MEMORY_SCOPE_AGENT);
        }
    }
}

// out[b][tag] = last1[b] . Wout[tag] + bout[tag]   (fp32)
__global__ __launch_bounds__(64) void k_out(const float* __restrict__ last1,
                                            const float* __restrict__ Wout,
                                            const float* __restrict__ bout,
                                            float* __restrict__ out) {
    int b = blockIdx.x, tg = blockIdx.y, lane = threadIdx.x;
    float sum = 0.f;
    for (int d = lane; d < H_; d += 64)
        sum += last1[(size_t)b * H_ + d] * Wout[(size_t)tg * H_ + d];
    #pragma unroll
    for (int off = 32; off; off >>= 1) sum += __shfl_xor(sum, off);
    if (lane == 0) out[b * TAGS_ + tg] = sum + bout[tg];
}

// ---------------- host ----------------

extern "C" void kernel_launch(void* const* d_in, const int* in_sizes, int n_in,
                              void* d_out, int out_size, void* d_ws, size_t ws_size,
                              hipStream_t stream)
{
    const int*   x    = (const int*)  d_in[0];
    const float* emb  = (const float*)d_in[1];
    const float* Wih0 = (const float*)d_in[2];
    const float* Whh0 = (const float*)d_in[3];
    const float* bih0 = (const float*)d_in[4];
    const float* bhh0 = (const float*)d_in[5];
    const float* Wih1 = (const float*)d_in[6];
    const float* Whh1 = (const float*)d_in[7];
    const float* bih1 = (const float*)d_in[8];
    const float* bhh1 = (const float*)d_in[9];
    const float* Wout = (const float*)d_in[10];
    const float* bout = (const float*)d_in[11];
    float* out = (float*)d_out;

    char* p = (char*)d_ws;
    bf16* E    = (bf16*)p;  p += (size_t)T_ * B_ * H_ * 2;      // 32 MB
    bf16* W0x  = (bf16*)p;  p += (size_t)G_ * H_ * 2;
    bf16* W0h  = (bf16*)p;  p += (size_t)G_ * H_ * 2;
    bf16* W1x  = (bf16*)p;  p += (size_t)G_ * H_ * 2;
    bf16* W1h  = (bf16*)p;  p += (size_t)G_ * H_ * 2;
    float* bias0 = (float*)p; p += (size_t)G_ * 4;
    float* bias1 = (float*)p; p += (size_t)G_ * 4;
    char* zbase = p;                                            // zeroed every launch
    bf16* h0ring = (bf16*)p; p += (size_t)8 * B_ * H_ * 2;      // 512 KB
    bf16* h1ring = (bf16*)p; p += (size_t)8 * B_ * H_ * 2;      // 512 KB
    int*  counters = (int*)p; p += 8 * 32 * 4;                  // 8 group counters, 128B apart
    size_t zbytes = (size_t)(p - zbase);
    float* last1 = (float*)p; p += (size_t)B_ * H_ * 4;
    int* lens = (int*)p; p += 256;

    k_zero<<<dim3(128), dim3(256), 0, stream>>>((uint32_t*)zbase, (int)(zbytes / 4));
    k_lens<<<dim3(B_), dim3(256), 0, stream>>>(x, lens);
    k_f2b<<<dim3(512), dim3(256), 0, stream>>>(Wih0, W0x, G_ * H_);
    k_f2b<<<dim3(512), dim3(256), 0, stream>>>(Whh0, W0h, G_ * H_);
    k_f2b<<<dim3(512), dim3(256), 0, stream>>>(Wih1, W1x, G_ * H_);
    k_f2b<<<dim3(512), dim3(256), 0, stream>>>(Whh1, W1h, G_ * H_);
    k_addb<<<dim3(8), dim3(256), 0, stream>>>(bih0, bhh0, bias0, G_);
    k_addb<<<dim3(8), dim3(256), 0, stream>>>(bih1, bhh1, bias1, G_);
    k_gather<<<dim3(T_, B_), dim3(256), 0, stream>>>(x, emb, E);

    k_lstm<<<dim3(256), dim3(256), 0, stream>>>(E, W0x, W0h, bias0, W1x, W1h, bias1,
                                                h0ring, h1ring, last1, lens, counters);

    k_out<<<dim3(B_, TAGS_), dim3(64), 0, stream>>>(last1, Wout, bout, out);
}